// Round 6
// baseline (328.933 us; speedup 1.0000x reference)
//
#include <hip/hip_runtime.h>
#include <hip/hip_bf16.h>
#include <hip/hip_cooperative_groups.h>

namespace cg = cooperative_groups;

// SelfAttention: B=4, S=2048, D=1024, fp32 in/out.
// Round 14: ONE cooperative launch (256 blocks x 512 thr, 1 block/CU).
// Sections separated by grid.sync(); GEMM loop bodies verbatim from R13:
//   S0 prep: cast x (16 float4/thr) + 3 weight transposes (LDS-tiled).
//   S1 qkvt: QK 256x256 8-phase + VT 128x256 half-tile (61.4us standalone).
//   S2 scores: 256x256 8-phase, exp epilogue + lpart partials.
//   S3 pv: 128x256 8-phase K=2048, /l epilogue.
// New hazard handled: leftover counted-vmcnt staged loads must be drained
// (VM0) before each grid.sync, else they'd land on the next section's LDS.
// Rationale: R8..R13 totals all exceed sum-of-kernels by ~50us (launch
// gaps ~12us each); bodies are at the template's ~840 TF K=1024 ceiling.

typedef _Float16 half_t;
typedef _Float16 half8 __attribute__((ext_vector_type(8)));
typedef _Float16 half4v __attribute__((ext_vector_type(4)));
typedef float f32x4 __attribute__((ext_vector_type(4)));

__device__ __forceinline__ void load16_to_lds(const half_t* g, half_t* l) {
  __builtin_amdgcn_global_load_lds(
      (const __attribute__((address_space(1))) void*)g,
      (__attribute__((address_space(3))) void*)l, 16, 0, 0);
}

#define LGKM0 asm volatile("s_waitcnt lgkmcnt(0)" ::: "memory")
#define LGKM8 asm volatile("s_waitcnt lgkmcnt(8)" ::: "memory")
#define VM0   asm volatile("s_waitcnt vmcnt(0)" ::: "memory")
#define VM4   asm volatile("s_waitcnt vmcnt(4)" ::: "memory")
#define VM6   asm volatile("s_waitcnt vmcnt(6)" ::: "memory")
#define BAR   __builtin_amdgcn_s_barrier()
#define PRIO1 __builtin_amdgcn_s_setprio(1)
#define PRIO0 __builtin_amdgcn_s_setprio(0)

__global__ __launch_bounds__(512, 2) void fused_attn(
    const float* __restrict__ x, const float* __restrict__ Wq,
    const float* __restrict__ Wk, const float* __restrict__ Wv,
    half_t* __restrict__ xh, half_t* __restrict__ wt,
    half_t* __restrict__ qk, half_t* __restrict__ vtg,
    half_t* __restrict__ sc, float* __restrict__ lpart,
    float* __restrict__ out) {
  __shared__ __align__(16) half_t As[2][256 * 64];
  __shared__ __align__(16) half_t Bs[2][256 * 64];
  __shared__ float linv[128];

  cg::grid_group gg = cg::this_grid();

  const int t    = threadIdx.x;
  const int lane = t & 63;
  const int wave = t >> 6;
  const int lm   = lane & 15;
  const int lq   = lane >> 4;
  const int pos0 = (lq ^ (lm & 7)) * 8;
  const int pos1 = ((4 + lq) ^ (lm & 7)) * 8;
  const int t8   = t * 8;
  const int trow = t >> 3;
  const int tchk = (t & 7) ^ (trow & 7);
  const int wr128 = (wave >> 2) * 128;
  const int wc64  = (wave & 3) * 64;

  // ========================= S0: prep ======================================
  {
    // cast x: 2,097,152 float4s over 131,072 threads = 16 each
    const int gtid = blockIdx.x * 512 + t;
#pragma unroll
    for (int k = 0; k < 16; ++k) {
      const size_t i = ((size_t)gtid + (size_t)k * 131072) * 4;
      const float4 v = *reinterpret_cast<const float4*>(x + i);
      half4v o;
      o.x = (half_t)v.x; o.y = (half_t)v.y; o.z = (half_t)v.z; o.w = (half_t)v.w;
      *reinterpret_cast<half4v*>(xh + i) = o;
    }
    // transpose Wq/Wk/Wv: 3072 32x32 tiles; 12/block, 2 at a time (256 thr ea)
    half_t (*tp)[32][33] = reinterpret_cast<half_t (*)[32][33]>(&As[0][0]);
    const int sub = t >> 8;
    const int tt  = t & 255;
    const int tx = tt & 31, ty = tt >> 5;
    for (int it = 0; it < 6; ++it) {
      const int tile = blockIdx.x * 12 + it * 2 + sub;
      const int w    = tile >> 10;
      const int rem  = tile & 1023;
      const float* in = (w == 0) ? Wq : (w == 1) ? Wk : Wv;
      half_t* o = wt + (size_t)w * 1024 * 1024;
      const int r0 = (rem >> 5) * 32, c0 = (rem & 31) * 32;
      __syncthreads();
#pragma unroll
      for (int i2 = 0; i2 < 32; i2 += 8)
        tp[sub][ty + i2][tx] =
            (half_t)in[(size_t)(r0 + ty + i2) * 1024 + c0 + tx];
      __syncthreads();
#pragma unroll
      for (int i2 = 0; i2 < 32; i2 += 8)
        o[(size_t)(c0 + ty + i2) * 1024 + r0 + tx] = tp[sub][tx][ty + i2];
    }
    VM0;
  }
  gg.sync();

  // ========================= S1: qkvt ======================================
  {
    const int b = blockIdx.x;
    const int xc = b & 7, j = b >> 3;
    const int m0 = (xc * 4 + (j & 3)) * 256;
    const int n0 = (j >> 2) * 256;

    const half_t* gA0 = xh + (size_t)(m0 + trow) * 1024 + tchk * 8;
    const half_t* gB0 = wt + (size_t)(n0 + trow) * 1024 + tchk * 8;

    f32x4 acc[8][4] = {};
    half8 va[4][2], vb0[2][2], vb1[2][2];

#define ST_A(buf, h, kt) do {                                                  \
    load16_to_lds(gA0 + (size_t)((h)*128) * 1024 + (size_t)(kt) * 64,          \
                  &As[buf][(h)*128*64] + t8);                                  \
    load16_to_lds(gA0 + (size_t)((h)*128+64) * 1024 + (size_t)(kt) * 64,       \
                  &As[buf][((h)*128+64)*64] + t8);                             \
  } while (0)
#define ST_B(buf, h, kt) do {                                                  \
    load16_to_lds(gB0 + (size_t)((h)*128) * 1024 + (size_t)(kt) * 64,          \
                  &Bs[buf][(h)*128*64] + t8);                                  \
    load16_to_lds(gB0 + (size_t)((h)*128+64) * 1024 + (size_t)(kt) * 64,       \
                  &Bs[buf][((h)*128+64)*64] + t8);                             \
  } while (0)
#define RD_A(buf, mh) do {                                                     \
    _Pragma("unroll") for (int m = 0; m < 4; ++m) {                            \
      const int ar = wr128 + (mh)*64 + m * 16 + lm;                            \
      va[m][0] = *(const half8*)&As[buf][ar * 64 + pos0];                      \
      va[m][1] = *(const half8*)&As[buf][ar * 64 + pos1];                      \
    } } while (0)
#define RD_B(buf, nh, vb) do {                                                 \
    _Pragma("unroll") for (int n = 0; n < 2; ++n) {                            \
      const int br = wc64 + (nh)*32 + n * 16 + lm;                             \
      vb[n][0] = *(const half8*)&Bs[buf][br * 64 + pos0];                      \
      vb[n][1] = *(const half8*)&Bs[buf][br * 64 + pos1];                      \
    } } while (0)
#define MF_Q(mh, nh, vb) do {                                                  \
    _Pragma("unroll") for (int kk = 0; kk < 2; ++kk)                           \
    _Pragma("unroll") for (int m = 0; m < 4; ++m)                              \
    _Pragma("unroll") for (int n = 0; n < 2; ++n)                              \
      acc[(mh)*4+m][(nh)*2+n] = __builtin_amdgcn_mfma_f32_16x16x32_f16(        \
          va[m][kk], vb[n][kk], acc[(mh)*4+m][(nh)*2+n], 0, 0, 0);             \
  } while (0)

    ST_A(0, 0, 0); ST_A(0, 1, 0);
    ST_B(0, 0, 0); ST_B(0, 1, 0);
    ST_B(1, 0, 1); ST_B(1, 1, 1);
    VM4;
    BAR;

#pragma unroll 1
    for (int i = 0; i < 8; ++i) {
      const int st1 = (2 * i + 1 < 15) ? 2 * i + 1 : 15;
      const int st2 = (2 * i + 2 < 15) ? 2 * i + 2 : 15;
      const int st3 = (2 * i + 3 < 15) ? 2 * i + 3 : 15;
      // P1
      RD_A(0, 0); RD_B(0, 0, vb0);
      ST_A(1, 0, st1);
      LGKM8;
      BAR; LGKM0;
      PRIO1; MF_Q(0, 0, vb0); PRIO0;
      BAR;
      // P2
      RD_B(0, 1, vb1);
      ST_A(1, 1, st1);
      BAR; LGKM0;
      PRIO1; MF_Q(0, 1, vb1); PRIO0;
      BAR;
      // P3
      RD_A(0, 1);
      ST_B(0, 0, st2);
      BAR; LGKM0;
      PRIO1; MF_Q(1, 0, vb0); PRIO0;
      BAR;
      // P4
      ST_B(0, 1, st2);
      BAR; LGKM0;
      PRIO1; MF_Q(1, 1, vb1); PRIO0;
      VM4;
      BAR;
      // P5
      RD_A(1, 0); RD_B(1, 0, vb0);
      ST_A(0, 0, st2);
      LGKM8;
      BAR; LGKM0;
      PRIO1; MF_Q(0, 0, vb0); PRIO0;
      BAR;
      // P6
      RD_B(1, 1, vb1);
      ST_A(0, 1, st2);
      BAR; LGKM0;
      PRIO1; MF_Q(0, 1, vb1); PRIO0;
      BAR;
      // P7
      RD_A(1, 1);
      ST_B(1, 0, st3);
      BAR; LGKM0;
      PRIO1; MF_Q(1, 0, vb0); PRIO0;
      BAR;
      // P8
      ST_B(1, 1, st3);
      BAR; LGKM0;
      PRIO1; MF_Q(1, 1, vb1); PRIO0;
      VM4;
      BAR;
    }

#pragma unroll
    for (int m = 0; m < 8; ++m)
#pragma unroll
      for (int n = 0; n < 4; ++n) {
        const int col = n0 + wc64 + n * 16 + lm;
#pragma unroll
        for (int r = 0; r < 4; ++r) {
          const int row = m0 + wr128 + m * 16 + lq * 4 + r;
          qk[(size_t)row * 2048 + col] = (half_t)acc[m][n][r];
        }
      }
#undef ST_A
#undef ST_B
#undef RD_A
#undef RD_B
#undef MF_Q

    // ---- VT half-tile: 128x256, K=1024 ----
    const int m0v = (j >> 2) * 128;
    const int n0v = (xc * 4 + (j & 3)) * 256;
    const int wmv = (wave >> 2) * 64;
    const int wnv = (wave & 3) * 64;

    const half_t* gA2 = wt + (size_t)2 * 1024 * 1024 +
                        (size_t)(m0v + trow) * 1024 + tchk * 8;
    const half_t* gB2 = xh + (size_t)(n0v + trow) * 1024 + tchk * 8;

    f32x4 acc2[4][4] = {};

#define ST_A2(buf, kt) do {                                                    \
    load16_to_lds(gA2 + (size_t)(kt) * 64, &As[buf][0] + t8);                  \
    load16_to_lds(gA2 + (size_t)64 * 1024 + (size_t)(kt) * 64,                 \
                  &As[buf][64*64] + t8);                                       \
  } while (0)
#define ST_B2(buf, h, kt) do {                                                 \
    load16_to_lds(gB2 + (size_t)((h)*128) * 1024 + (size_t)(kt) * 64,          \
                  &Bs[buf][(h)*128*64] + t8);                                  \
    load16_to_lds(gB2 + (size_t)((h)*128+64) * 1024 + (size_t)(kt) * 64,       \
                  &Bs[buf][((h)*128+64)*64] + t8);                             \
  } while (0)
#define RD_A2(buf, mh) do {                                                    \
    _Pragma("unroll") for (int m = 0; m < 2; ++m) {                            \
      const int ar = wmv + (mh)*32 + m * 16 + lm;                              \
      va[(mh)*2+m][0] = *(const half8*)&As[buf][ar * 64 + pos0];               \
      va[(mh)*2+m][1] = *(const half8*)&As[buf][ar * 64 + pos1];               \
    } } while (0)
#define RD_B2(buf, nh, vb) do {                                                \
    _Pragma("unroll") for (int n = 0; n < 2; ++n) {                            \
      const int br = wnv + (nh)*32 + n * 16 + lm;                              \
      vb[n][0] = *(const half8*)&Bs[buf][br * 64 + pos0];                      \
      vb[n][1] = *(const half8*)&Bs[buf][br * 64 + pos1];                      \
    } } while (0)
#define MF_V(mh, nh, vb) do {                                                  \
    _Pragma("unroll") for (int kk = 0; kk < 2; ++kk)                           \
    _Pragma("unroll") for (int m = 0; m < 2; ++m)                              \
    _Pragma("unroll") for (int n = 0; n < 2; ++n)                              \
      acc2[(mh)*2+m][(nh)*2+n] = __builtin_amdgcn_mfma_f32_16x16x32_f16(       \
          va[(mh)*2+m][kk], vb[n][kk], acc2[(mh)*2+m][(nh)*2+n], 0, 0, 0);     \
  } while (0)

    VM0;
    ST_B2(0, 0, 0); ST_B2(0, 1, 0); ST_A2(0, 0);
    ST_B2(1, 0, 1); ST_B2(1, 1, 1); ST_A2(1, 1);
    VM6;
    BAR;

#pragma unroll 1
    for (int i = 0; i < 8; ++i) {
      const int t2 = (2 * i + 2 < 15) ? 2 * i + 2 : 15;
      const int t3 = (2 * i + 3 < 15) ? 2 * i + 3 : 15;
      // P1
      RD_A2(0, 0); RD_B2(0, 0, vb0);
      BAR; LGKM0;
      PRIO1; MF_V(0, 0, vb0); PRIO0;
      BAR;
      // P2
      RD_B2(0, 1, vb1);
      BAR; LGKM0;
      PRIO1; MF_V(0, 1, vb1); PRIO0;
      BAR;
      // P3
      RD_A2(0, 1);
      ST_B2(0, 0, t2);
      BAR; LGKM0;
      PRIO1; MF_V(1, 0, vb0); PRIO0;
      BAR;
      // P4
      ST_B2(0, 1, t2); ST_A2(0, t2);
      BAR; LGKM0;
      PRIO1; MF_V(1, 1, vb1); PRIO0;
      VM6;
      BAR;
      // P5
      RD_A2(1, 0); RD_B2(1, 0, vb0);
      BAR; LGKM0;
      PRIO1; MF_V(0, 0, vb0); PRIO0;
      BAR;
      // P6
      RD_B2(1, 1, vb1);
      BAR; LGKM0;
      PRIO1; MF_V(0, 1, vb1); PRIO0;
      BAR;
      // P7
      RD_A2(1, 1);
      ST_B2(1, 0, t3);
      BAR; LGKM0;
      PRIO1; MF_V(1, 0, vb0); PRIO0;
      BAR;
      // P8
      ST_B2(1, 1, t3); ST_A2(1, t3);
      BAR; LGKM0;
      PRIO1; MF_V(1, 1, vb1); PRIO0;
      VM6;
      BAR;
    }

#pragma unroll
    for (int m = 0; m < 4; ++m)
#pragma unroll
      for (int n = 0; n < 4; ++n) {
        const int col = n0v + wnv + n * 16 + lm;
#pragma unroll
        for (int r = 0; r < 4; ++r) {
          const int row = m0v + wmv + m * 16 + lq * 4 + r;
          vtg[(size_t)row * 8192 + col] = (half_t)acc2[m][n][r];
        }
      }
#undef ST_A2
#undef ST_B2
#undef RD_A2
#undef RD_B2
#undef MF_V
    VM0;
  }
  gg.sync();

  // ========================= S2: scores ====================================
  {
    const int id = blockIdx.x;
    const int xc = id & 7, j = id >> 3;
    const int bx = j & 7;
    const int z  = xc >> 1;
    const int by = (xc & 1) * 4 + (j >> 3);
    const int m0 = by * 256;
    const int n0 = bx * 256;
    const half_t* A  = qk + (size_t)z * 2048 * 2048;
    const half_t* Bm = A + 1024;
    half_t* C = sc + (size_t)z * 2048 * 2048;

    const half_t* gA0 = A  + (size_t)(m0 + trow) * 2048 + tchk * 8;
    const half_t* gB0 = Bm + (size_t)(n0 + trow) * 2048 + tchk * 8;

    f32x4 acc[8][4] = {};
    half8 va[4][2], vb0[2][2], vb1[2][2];

#define ST_A(buf, h, kt) do {                                                  \
    load16_to_lds(gA0 + (size_t)((h)*128) * 2048 + (size_t)(kt) * 64,          \
                  &As[buf][(h)*128*64] + t8);                                  \
    load16_to_lds(gA0 + (size_t)((h)*128+64) * 2048 + (size_t)(kt) * 64,       \
                  &As[buf][((h)*128+64)*64] + t8);                             \
  } while (0)
#define ST_B(buf, h, kt) do {                                                  \
    load16_to_lds(gB0 + (size_t)((h)*128) * 2048 + (size_t)(kt) * 64,          \
                  &Bs[buf][(h)*128*64] + t8);                                  \
    load16_to_lds(gB0 + (size_t)((h)*128+64) * 2048 + (size_t)(kt) * 64,       \
                  &Bs[buf][((h)*128+64)*64] + t8);                             \
  } while (0)
#define RD_A(buf, mh) do {                                                     \
    _Pragma("unroll") for (int m = 0; m < 4; ++m) {                            \
      const int ar = wr128 + (mh)*64 + m * 16 + lm;                            \
      va[m][0] = *(const half8*)&As[buf][ar * 64 + pos0];                      \
      va[m][1] = *(const half8*)&As[buf][ar * 64 + pos1];                      \
    } } while (0)
#define RD_B(buf, nh, vb) do {                                                 \
    _Pragma("unroll") for (int n = 0; n < 2; ++n) {                            \
      const int br = wc64 + (nh)*32 + n * 16 + lm;                             \
      vb[n][0] = *(const half8*)&Bs[buf][br * 64 + pos0];                      \
      vb[n][1] = *(const half8*)&Bs[buf][br * 64 + pos1];                      \
    } } while (0)
#define MF_Q(mh, nh, vb) do {                                                  \
    _Pragma("unroll") for (int kk = 0; kk < 2; ++kk)                           \
    _Pragma("unroll") for (int m = 0; m < 4; ++m)                              \
    _Pragma("unroll") for (int n = 0; n < 2; ++n)                              \
      acc[(mh)*4+m][(nh)*2+n] = __builtin_amdgcn_mfma_f32_16x16x32_f16(        \
          va[m][kk], vb[n][kk], acc[(mh)*4+m][(nh)*2+n], 0, 0, 0);             \
  } while (0)

    ST_A(0, 0, 0); ST_A(0, 1, 0);
    ST_B(0, 0, 0); ST_B(0, 1, 0);
    ST_B(1, 0, 1); ST_B(1, 1, 1);
    VM4;
    BAR;

#pragma unroll 1
    for (int i = 0; i < 8; ++i) {
      const int st1 = (2 * i + 1 < 15) ? 2 * i + 1 : 15;
      const int st2 = (2 * i + 2 < 15) ? 2 * i + 2 : 15;
      const int st3 = (2 * i + 3 < 15) ? 2 * i + 3 : 15;
      // P1
      RD_A(0, 0); RD_B(0, 0, vb0);
      ST_A(1, 0, st1);
      LGKM8;
      BAR; LGKM0;
      PRIO1; MF_Q(0, 0, vb0); PRIO0;
      BAR;
      // P2
      RD_B(0, 1, vb1);
      ST_A(1, 1, st1);
      BAR; LGKM0;
      PRIO1; MF_Q(0, 1, vb1); PRIO0;
      BAR;
      // P3
      RD_A(0, 1);
      ST_B(0, 0, st2);
      BAR; LGKM0;
      PRIO1; MF_Q(1, 0, vb0); PRIO0;
      BAR;
      // P4
      ST_B(0, 1, st2);
      BAR; LGKM0;
      PRIO1; MF_Q(1, 1, vb1); PRIO0;
      VM4;
      BAR;
      // P5
      RD_A(1, 0); RD_B(1, 0, vb0);
      ST_A(0, 0, st2);
      LGKM8;
      BAR; LGKM0;
      PRIO1; MF_Q(0, 0, vb0); PRIO0;
      BAR;
      // P6
      RD_B(1, 1, vb1);
      ST_A(0, 1, st2);
      BAR; LGKM0;
      PRIO1; MF_Q(0, 1, vb1); PRIO0;
      BAR;
      // P7
      RD_A(1, 1);
      ST_B(1, 0, st3);
      BAR; LGKM0;
      PRIO1; MF_Q(1, 0, vb0); PRIO0;
      BAR;
      // P8
      ST_B(1, 1, st3);
      BAR; LGKM0;
      PRIO1; MF_Q(1, 1, vb1); PRIO0;
      VM4;
      BAR;
    }

    const float scale = 1.0f / 32.0f;
#pragma unroll
    for (int m = 0; m < 8; ++m)
#pragma unroll
      for (int r = 0; r < 4; ++r) {
        const int row = m0 + wr128 + m * 16 + lq * 4 + r;
        float s = 0.f;
#pragma unroll
        for (int n = 0; n < 4; ++n) {
          const int col = n0 + wc64 + n * 16 + lm;
          float v = __expf(acc[m][n][r] * scale - 8.0f);
          s += v;
          C[(size_t)row * 2048 + col] = (half_t)v;
        }
        s += __shfl_xor(s, 1); s += __shfl_xor(s, 2);
        s += __shfl_xor(s, 4); s += __shfl_xor(s, 8);
        if (lm == 0)
          lpart[((size_t)z * 2048 + row) * 32 + bx * 4 + (wave & 3)] = s;
      }
#undef ST_A
#undef ST_B
#undef RD_A
#undef RD_B
#undef MF_Q
    VM0;
  }
  gg.sync();

  // ========================= S3: pv ========================================
  {
    const int id = blockIdx.x;
    const int xc = id & 7, j = id >> 3;
    const int z  = xc >> 1;
    const int m0 = ((xc & 1) * 8 + (j >> 2)) * 128;
    const int n0 = (j & 3) * 256;
    const half_t* A  = sc  + (size_t)z * 2048 * 2048;
    const half_t* Bm = vtg + (size_t)z * 2048;
    float* C = out + (size_t)z * 2048 * 1024;

    const int wmv = (wave >> 2) * 64;
    const int wnv = (wave & 3) * 64;

    if (t < 128) {
      const float4* lp =
          (const float4*)&lpart[((size_t)z * 2048 + m0 + t) * 32];
      float s = 0.f;
#pragma unroll
      for (int p = 0; p < 8; ++p) {
        float4 v = lp[p];
        s += v.x + v.y + v.z + v.w;
      }
      linv[t] = 1.0f / s;
    }

    const half_t* gA2 = A  + (size_t)(m0 + trow) * 2048 + tchk * 8;
    const half_t* gB2 = Bm + (size_t)(n0 + trow) * 8192 + tchk * 8;

    f32x4 acc2[4][4] = {};
    half8 va[4][2], vb0[2][2], vb1[2][2];

#define ST_A2(buf, kt) do {                                                    \
    load16_to_lds(gA2 + (size_t)(kt) * 64, &As[buf][0] + t8);                  \
    load16_to_lds(gA2 + (size_t)64 * 2048 + (size_t)(kt) * 64,                 \
                  &As[buf][64*64] + t8);                                       \
  } while (0)
#define ST_B2(buf, h, kt) do {                                                 \
    load16_to_lds(gB2 + (size_t)((h)*128) * 8192 + (size_t)(kt) * 64,          \
                  &Bs[buf][(h)*128*64] + t8);                                  \
    load16_to_lds(gB2 + (size_t)((h)*128+64) * 8192 + (size_t)(kt) * 64,       \
                  &Bs[buf][((h)*128+64)*64] + t8);                             \
  } while (0)
#define RD_A2(buf, mh) do {                                                    \
    _Pragma("unroll") for (int m = 0; m < 2; ++m) {                            \
      const int ar = wmv + (mh)*32 + m * 16 + lm;                              \
      va[(mh)*2+m][0] = *(const half8*)&As[buf][ar * 64 + pos0];               \
      va[(mh)*2+m][1] = *(const half8*)&As[buf][ar * 64 + pos1];               \
    } } while (0)
#define RD_B2(buf, nh, vb) do {                                                \
    _Pragma("unroll") for (int n = 0; n < 2; ++n) {                            \
      const int br = wnv + (nh)*32 + n * 16 + lm;                              \
      vb[n][0] = *(const half8*)&Bs[buf][br * 64 + pos0];                      \
      vb[n][1] = *(const half8*)&Bs[buf][br * 64 + pos1];                      \
    } } while (0)
#define MF_V(mh, nh, vb) do {                                                  \
    _Pragma("unroll") for (int kk = 0; kk < 2; ++kk)                           \
    _Pragma("unroll") for (int m = 0; m < 2; ++m)                              \
    _Pragma("unroll") for (int n = 0; n < 2; ++n)                              \
      acc2[(mh)*2+m][(nh)*2+n] = __builtin_amdgcn_mfma_f32_16x16x32_f16(       \
          va[(mh)*2+m][kk], vb[n][kk], acc2[(mh)*2+m][(nh)*2+n], 0, 0, 0);     \
  } while (0)

    ST_B2(0, 0, 0); ST_B2(0, 1, 0); ST_A2(0, 0);
    ST_B2(1, 0, 1); ST_B2(1, 1, 1); ST_A2(1, 1);
    VM6;
    BAR;

#pragma unroll 1
    for (int i = 0; i < 16; ++i) {
      const int t2 = (2 * i + 2 < 31) ? 2 * i + 2 : 31;
      const int t3 = (2 * i + 3 < 31) ? 2 * i + 3 : 31;
      // P1
      RD_A2(0, 0); RD_B2(0, 0, vb0);
      BAR; LGKM0;
      PRIO1; MF_V(0, 0, vb0); PRIO0;
      BAR;
      // P2
      RD_B2(0, 1, vb1);
      BAR; LGKM0;
      PRIO1; MF_V(0, 1, vb1); PRIO0;
      BAR;
      // P3
      RD_A2(0, 1);
      ST_B2(0, 0, t2);
      BAR; LGKM0;
      PRIO1; MF_V(1, 0, vb0); PRIO0;
      BAR;
      // P4
      ST_B2(0, 1, t2); ST_A2(0, t2);
      BAR; LGKM0;
      PRIO1; MF_V(1, 1, vb1); PRIO0;
      VM6;
      BAR;
      // P5
      RD_A2(1, 0); RD_B2(1, 0, vb0);
      BAR; LGKM0;
      PRIO1; MF_V(0, 0, vb0); PRIO0;
      BAR;
      // P6
      RD_B2(1, 1, vb1);
      BAR; LGKM0;
      PRIO1; MF_V(0, 1, vb1); PRIO0;
      BAR;
      // P7
      RD_A2(1, 1);
      ST_B2(1, 0, t3);
      BAR; LGKM0;
      PRIO1; MF_V(1, 0, vb0); PRIO0;
      BAR;
      // P8
      ST_B2(1, 1, t3); ST_A2(1, t3);
      BAR; LGKM0;
      PRIO1; MF_V(1, 1, vb1); PRIO0;
      VM6;
      BAR;
    }

#pragma unroll
    for (int m = 0; m < 4; ++m)
#pragma unroll
      for (int r = 0; r < 4; ++r) {
        const int lrow = wmv + m * 16 + lq * 4 + r;
        const float inv = linv[lrow];
        const int row = m0 + lrow;
#pragma unroll
        for (int n = 0; n < 4; ++n) {
          const int col = n0 + wnv + n * 16 + lm;
          C[(size_t)row * 1024 + col] = acc2[m][n][r] * inv;
        }
      }
#undef ST_A2
#undef ST_B2
#undef RD_A2
#undef RD_B2
#undef MF_V
  }
}

extern "C" void kernel_launch(void* const* d_in, const int* in_sizes, int n_in,
                              void* d_out, int out_size, void* d_ws, size_t ws_size,
                              hipStream_t stream) {
  constexpr int Bb = 4, S = 2048, D = 1024;
  constexpr size_t MS = (size_t)Bb * S;  // 8192 rows

  const float* x  = (const float*)d_in[0];
  const float* Wq = (const float*)d_in[1];
  const float* Wk = (const float*)d_in[2];
  const float* Wv = (const float*)d_in[3];
  float* out = (float*)d_out;

  // Workspace carve (~103 MB).
  char* p = (char*)d_ws;
  half_t* xh    = (half_t*)p; p += MS * D * 2;               // 16 MB
  half_t* wt    = (half_t*)p; p += (size_t)3 * D * D * 2;    // 6 MB  [Wq|Wk|Wv]^T
  half_t* qk    = (half_t*)p; p += MS * (size_t)(2 * D) * 2; // 32 MB [B*S, 2D]
  half_t* vtg   = (half_t*)p; p += (size_t)D * MS * 2;       // 16 MB [D, B*S]
  half_t* sc    = (half_t*)p; p += (size_t)Bb * S * S * 2;   // 32 MB P=exp(s-8)
  float*  lpart = (float*)p;  p += MS * 32 * 4;              // 1 MB partial sums

  void* args[] = {(void*)&x,  (void*)&Wq, (void*)&Wk,  (void*)&Wv,
                  (void*)&xh, (void*)&wt, (void*)&qk,  (void*)&vtg,
                  (void*)&sc, (void*)&lpart, (void*)&out};
  hipLaunchCooperativeKernel((const void*)fused_attn, dim3(256), dim3(512),
                             args, 0, stream);
}

// Round 7
// 223.477 us; speedup vs baseline: 1.4719x; 1.4719x over previous
//
#include <hip/hip_runtime.h>
#include <hip/hip_bf16.h>

// SelfAttention: B=4, S=2048, D=1024, fp32 in/out.
// Round 15: revert cooperative fusion (R14: grid.sync cost + XCD L2
// flush made fused 245us > 167us sum; total 329). Back to R13's 4
// launches, with ONE change: VT and pv loops merged 8->4 phases/iter
// (16 MFMA per barrier-pair, matching QK's proven density; barriers
// 16->6 per iter). Stage-after-read windows and counted-vmcnt ledger
// re-derived (Pb VM6 drains prev Pd's buf1 loads; Pd drains Pb's buf0).
//  - qkvt_gemm8: QK 256x256 8-phase verbatim + VT 128x256 4-phase.
//  - scores_gemm8: unchanged (256x256 8-phase + exp/lpart epilogue).
//  - pv_gemm8: 128x256 4-phase, K=2048 (16 iters), /l epilogue.
//  - prep: unchanged.

typedef _Float16 half_t;
typedef _Float16 half8 __attribute__((ext_vector_type(8)));
typedef _Float16 half4v __attribute__((ext_vector_type(4)));
typedef float f32x4 __attribute__((ext_vector_type(4)));

__device__ __forceinline__ void load16_to_lds(const half_t* g, half_t* l) {
  __builtin_amdgcn_global_load_lds(
      (const __attribute__((address_space(1))) void*)g,
      (__attribute__((address_space(3))) void*)l, 16, 0, 0);
}

#define LGKM0 asm volatile("s_waitcnt lgkmcnt(0)" ::: "memory")
#define LGKM8 asm volatile("s_waitcnt lgkmcnt(8)" ::: "memory")
#define VM0   asm volatile("s_waitcnt vmcnt(0)" ::: "memory")
#define VM4   asm volatile("s_waitcnt vmcnt(4)" ::: "memory")
#define VM6   asm volatile("s_waitcnt vmcnt(6)" ::: "memory")
#define BAR   __builtin_amdgcn_s_barrier()
#define PRIO1 __builtin_amdgcn_s_setprio(1)
#define PRIO0 __builtin_amdgcn_s_setprio(0)

// --------- qkvt: QK 256x256 tile + VT 128x256 half-tile per block ----------
// Grid 256 x 512 threads. x = b&7 (XCD), j = b>>3.
__global__ __launch_bounds__(512, 2) void qkvt_gemm8(
    const half_t* __restrict__ xh, const half_t* __restrict__ wt,
    half_t* __restrict__ qk, half_t* __restrict__ vtg) {
  __shared__ __align__(16) half_t As[2][256 * 64];
  __shared__ __align__(16) half_t Bs[2][256 * 64];

  const int b = blockIdx.x;
  const int x = b & 7, j = b >> 3;
  const int m0 = (x * 4 + (j & 3)) * 256;
  const int n0 = (j >> 2) * 256;

  const int t     = threadIdx.x;
  const int lane  = t & 63;
  const int wave  = t >> 6;
  const int wr128 = (wave >> 2) * 128;
  const int wc64  = (wave & 3) * 64;
  const int lm    = lane & 15;
  const int lq    = lane >> 4;
  const int pos0  = (lq ^ (lm & 7)) * 8;
  const int pos1  = ((4 + lq) ^ (lm & 7)) * 8;
  const int t8    = t * 8;

  const int trow = t >> 3;
  const int tchk = (t & 7) ^ (trow & 7);
  const half_t* gA0 = xh + (size_t)(m0 + trow) * 1024 + tchk * 8;
  const half_t* gB0 = wt + (size_t)(n0 + trow) * 1024 + tchk * 8;

  f32x4 acc[8][4] = {};
  half8 va[4][2], vb0[2][2], vb1[2][2];

#define ST_A(buf, h, kt) do {                                                  \
    load16_to_lds(gA0 + (size_t)((h)*128) * 1024 + (size_t)(kt) * 64,          \
                  &As[buf][(h)*128*64] + t8);                                  \
    load16_to_lds(gA0 + (size_t)((h)*128+64) * 1024 + (size_t)(kt) * 64,       \
                  &As[buf][((h)*128+64)*64] + t8);                             \
  } while (0)
#define ST_B(buf, h, kt) do {                                                  \
    load16_to_lds(gB0 + (size_t)((h)*128) * 1024 + (size_t)(kt) * 64,          \
                  &Bs[buf][(h)*128*64] + t8);                                  \
    load16_to_lds(gB0 + (size_t)((h)*128+64) * 1024 + (size_t)(kt) * 64,       \
                  &Bs[buf][((h)*128+64)*64] + t8);                             \
  } while (0)
#define RD_A(buf, mh) do {                                                     \
    _Pragma("unroll") for (int m = 0; m < 4; ++m) {                            \
      const int ar = wr128 + (mh)*64 + m * 16 + lm;                            \
      va[m][0] = *(const half8*)&As[buf][ar * 64 + pos0];                      \
      va[m][1] = *(const half8*)&As[buf][ar * 64 + pos1];                      \
    } } while (0)
#define RD_B(buf, nh, vb) do {                                                 \
    _Pragma("unroll") for (int n = 0; n < 2; ++n) {                            \
      const int br = wc64 + (nh)*32 + n * 16 + lm;                             \
      vb[n][0] = *(const half8*)&Bs[buf][br * 64 + pos0];                      \
      vb[n][1] = *(const half8*)&Bs[buf][br * 64 + pos1];                      \
    } } while (0)
#define MF_Q(mh, nh, vb) do {                                                  \
    _Pragma("unroll") for (int kk = 0; kk < 2; ++kk)                           \
    _Pragma("unroll") for (int m = 0; m < 4; ++m)                              \
    _Pragma("unroll") for (int n = 0; n < 2; ++n)                              \
      acc[(mh)*4+m][(nh)*2+n] = __builtin_amdgcn_mfma_f32_16x16x32_f16(        \
          va[m][kk], vb[n][kk], acc[(mh)*4+m][(nh)*2+n], 0, 0, 0);             \
  } while (0)

  ST_A(0, 0, 0); ST_A(0, 1, 0);
  ST_B(0, 0, 0); ST_B(0, 1, 0);
  ST_B(1, 0, 1); ST_B(1, 1, 1);
  VM4;
  BAR;

#pragma unroll 1
  for (int i = 0; i < 8; ++i) {
    const int st1 = (2 * i + 1 < 15) ? 2 * i + 1 : 15;
    const int st2 = (2 * i + 2 < 15) ? 2 * i + 2 : 15;
    const int st3 = (2 * i + 3 < 15) ? 2 * i + 3 : 15;
    // ---- P1
    RD_A(0, 0); RD_B(0, 0, vb0);
    ST_A(1, 0, st1);
    LGKM8;
    BAR; LGKM0;
    PRIO1; MF_Q(0, 0, vb0); PRIO0;
    BAR;
    // ---- P2
    RD_B(0, 1, vb1);
    ST_A(1, 1, st1);
    BAR; LGKM0;
    PRIO1; MF_Q(0, 1, vb1); PRIO0;
    BAR;
    // ---- P3
    RD_A(0, 1);
    ST_B(0, 0, st2);
    BAR; LGKM0;
    PRIO1; MF_Q(1, 0, vb0); PRIO0;
    BAR;
    // ---- P4
    ST_B(0, 1, st2);
    BAR; LGKM0;
    PRIO1; MF_Q(1, 1, vb1); PRIO0;
    VM4;
    BAR;
    // ---- P5
    RD_A(1, 0); RD_B(1, 0, vb0);
    ST_A(0, 0, st2);
    LGKM8;
    BAR; LGKM0;
    PRIO1; MF_Q(0, 0, vb0); PRIO0;
    BAR;
    // ---- P6
    RD_B(1, 1, vb1);
    ST_A(0, 1, st2);
    BAR; LGKM0;
    PRIO1; MF_Q(0, 1, vb1); PRIO0;
    BAR;
    // ---- P7
    RD_A(1, 1);
    ST_B(1, 0, st3);
    BAR; LGKM0;
    PRIO1; MF_Q(1, 0, vb0); PRIO0;
    BAR;
    // ---- P8
    ST_B(1, 1, st3);
    BAR; LGKM0;
    PRIO1; MF_Q(1, 1, vb1); PRIO0;
    VM4;
    BAR;
  }

  // 16x16 C/D: col=lane&15, row=(lane>>4)*4+reg  [m89/m91]
#pragma unroll
  for (int m = 0; m < 8; ++m)
#pragma unroll
    for (int n = 0; n < 4; ++n) {
      const int col = n0 + wc64 + n * 16 + lm;
#pragma unroll
      for (int r = 0; r < 4; ++r) {
        const int row = m0 + wr128 + m * 16 + lq * 4 + r;
        qk[(size_t)row * 2048 + col] = (half_t)acc[m][n][r];
      }
    }
#undef ST_A
#undef ST_B
#undef RD_A
#undef RD_B
#undef MF_Q

  // ============== VT half-tile: 128x256, K=1024, 4-phase ====================
  const int m0v = (j >> 2) * 128;
  const int n0v = (x * 4 + (j & 3)) * 256;
  const int wmv = (wave >> 2) * 64;
  const int wnv = (wave & 3) * 64;

  const half_t* gA2 = wt + (size_t)2 * 1024 * 1024 +
                      (size_t)(m0v + trow) * 1024 + tchk * 8;
  const half_t* gB2 = xh + (size_t)(n0v + trow) * 1024 + tchk * 8;

  f32x4 acc2[4][4] = {};

#define ST_A2(buf, kt) do {                                                    \
    load16_to_lds(gA2 + (size_t)(kt) * 64, &As[buf][0] + t8);                  \
    load16_to_lds(gA2 + (size_t)64 * 1024 + (size_t)(kt) * 64,                 \
                  &As[buf][64*64] + t8);                                       \
  } while (0)
#define ST_B2(buf, h, kt) do {                                                 \
    load16_to_lds(gB2 + (size_t)((h)*128) * 1024 + (size_t)(kt) * 64,          \
                  &Bs[buf][(h)*128*64] + t8);                                  \
    load16_to_lds(gB2 + (size_t)((h)*128+64) * 1024 + (size_t)(kt) * 64,       \
                  &Bs[buf][((h)*128+64)*64] + t8);                             \
  } while (0)
#define RD_A2(buf, mh) do {                                                    \
    _Pragma("unroll") for (int m = 0; m < 2; ++m) {                            \
      const int ar = wmv + (mh)*32 + m * 16 + lm;                              \
      va[(mh)*2+m][0] = *(const half8*)&As[buf][ar * 64 + pos0];               \
      va[(mh)*2+m][1] = *(const half8*)&As[buf][ar * 64 + pos1];               \
    } } while (0)
#define RD_B2(buf, nh, vb) do {                                                \
    _Pragma("unroll") for (int n = 0; n < 2; ++n) {                            \
      const int br = wnv + (nh)*32 + n * 16 + lm;                              \
      vb[n][0] = *(const half8*)&Bs[buf][br * 64 + pos0];                      \
      vb[n][1] = *(const half8*)&Bs[buf][br * 64 + pos1];                      \
    } } while (0)
#define MF_V(mh, nh, vb) do {                                                  \
    _Pragma("unroll") for (int kk = 0; kk < 2; ++kk)                           \
    _Pragma("unroll") for (int m = 0; m < 2; ++m)                              \
    _Pragma("unroll") for (int n = 0; n < 2; ++n)                              \
      acc2[(mh)*2+m][(nh)*2+n] = __builtin_amdgcn_mfma_f32_16x16x32_f16(       \
          va[(mh)*2+m][kk], vb[n][kk], acc2[(mh)*2+m][(nh)*2+n], 0, 0, 0);     \
  } while (0)

  // Drain QK's in-flight staged loads + epilogue stores before LDS reuse.
  VM0;
  ST_B2(0, 0, 0); ST_B2(0, 1, 0); ST_A2(0, 0);   // b0 <- K-tile 0
  ST_B2(1, 0, 1); ST_B2(1, 1, 1); ST_A2(1, 1);   // b1 <- K-tile 1
  VM6;
  BAR;

#pragma unroll 1
  for (int i = 0; i < 8; ++i) {
    const int t2 = (2 * i + 2 < 15) ? 2 * i + 2 : 15;
    const int t3 = (2 * i + 3 < 15) ? 2 * i + 3 : 15;
    // ---- Pa: read ALL buf0 frags; MFMA first half
    RD_A2(0, 0); RD_A2(0, 1); RD_B2(0, 0, vb0); RD_B2(0, 1, vb1);
    LGKM8;
    BAR; LGKM0;
    PRIO1; MF_V(0, 0, vb0); MF_V(0, 1, vb1); PRIO0;
    BAR;
    // ---- Pb: stage buf0<-t2 (reads done at Pa LGKM0); MFMA second half;
    //          VM6 drains prev Pd's 6 buf1 loads before Pc reads buf1.
    ST_B2(0, 0, t2); ST_B2(0, 1, t2); ST_A2(0, t2);
    PRIO1; MF_V(1, 0, vb0); MF_V(1, 1, vb1); PRIO0;
    VM6;
    BAR;
    // ---- Pc: read ALL buf1 frags; MFMA first half
    RD_A2(1, 0); RD_A2(1, 1); RD_B2(1, 0, vb0); RD_B2(1, 1, vb1);
    LGKM8;
    BAR; LGKM0;
    PRIO1; MF_V(0, 0, vb0); MF_V(0, 1, vb1); PRIO0;
    BAR;
    // ---- Pd: stage buf1<-t3; MFMA second half; VM6 drains Pb's buf0 loads.
    ST_B2(1, 0, t3); ST_B2(1, 1, t3); ST_A2(1, t3);
    PRIO1; MF_V(1, 0, vb0); MF_V(1, 1, vb1); PRIO0;
    VM6;
    BAR;
  }

#pragma unroll
  for (int m = 0; m < 4; ++m)
#pragma unroll
    for (int n = 0; n < 4; ++n) {
      const int col = n0v + wnv + n * 16 + lm;
#pragma unroll
      for (int r = 0; r < 4; ++r) {
        const int row = m0v + wmv + m * 16 + lq * 4 + r;
        vtg[(size_t)row * 8192 + col] = (half_t)acc2[m][n][r];
      }
    }
#undef ST_A2
#undef ST_B2
#undef RD_A2
#undef RD_B2
#undef MF_V
}

// ------------- scores: P = exp(qk^T/32 - 8), 256x256 tile, 8-phase ----------
__global__ __launch_bounds__(512, 2) void scores_gemm8(
    const half_t* __restrict__ qk, half_t* __restrict__ sc,
    float* __restrict__ lpart) {
  __shared__ __align__(16) half_t As[2][256 * 64];
  __shared__ __align__(16) half_t Bs[2][256 * 64];

  const int id  = blockIdx.x;
  const int x   = id & 7, j = id >> 3;
  const int bx  = j & 7;
  const int z   = x >> 1;
  const int by  = (x & 1) * 4 + (j >> 3);
  const int m0  = by * 256;
  const int n0  = bx * 256;
  const half_t* A  = qk + (size_t)z * 2048 * 2048;  // q rows (ld 2048)
  const half_t* Bm = A + 1024;                      // k rows
  half_t* C = sc + (size_t)z * 2048 * 2048;

  const int t     = threadIdx.x;
  const int lane  = t & 63;
  const int wave  = t >> 6;
  const int wr128 = (wave >> 2) * 128;
  const int wc64  = (wave & 3) * 64;
  const int lm    = lane & 15;
  const int lq    = lane >> 4;
  const int pos0  = (lq ^ (lm & 7)) * 8;
  const int pos1  = ((4 + lq) ^ (lm & 7)) * 8;
  const int t8    = t * 8;

  const int trow = t >> 3;
  const int tchk = (t & 7) ^ (trow & 7);
  const half_t* gA0 = A  + (size_t)(m0 + trow) * 2048 + tchk * 8;
  const half_t* gB0 = Bm + (size_t)(n0 + trow) * 2048 + tchk * 8;

  f32x4 acc[8][4] = {};
  half8 va[4][2], vb0[2][2], vb1[2][2];

#define ST_A(buf, h, kt) do {                                                  \
    load16_to_lds(gA0 + (size_t)((h)*128) * 2048 + (size_t)(kt) * 64,          \
                  &As[buf][(h)*128*64] + t8);                                  \
    load16_to_lds(gA0 + (size_t)((h)*128+64) * 2048 + (size_t)(kt) * 64,       \
                  &As[buf][((h)*128+64)*64] + t8);                             \
  } while (0)
#define ST_B(buf, h, kt) do {                                                  \
    load16_to_lds(gB0 + (size_t)((h)*128) * 2048 + (size_t)(kt) * 64,          \
                  &Bs[buf][(h)*128*64] + t8);                                  \
    load16_to_lds(gB0 + (size_t)((h)*128+64) * 2048 + (size_t)(kt) * 64,       \
                  &Bs[buf][((h)*128+64)*64] + t8);                             \
  } while (0)
#define RD_A(buf, mh) do {                                                     \
    _Pragma("unroll") for (int m = 0; m < 4; ++m) {                            \
      const int ar = wr128 + (mh)*64 + m * 16 + lm;                            \
      va[m][0] = *(const half8*)&As[buf][ar * 64 + pos0];                      \
      va[m][1] = *(const half8*)&As[buf][ar * 64 + pos1];                      \
    } } while (0)
#define RD_B(buf, nh, vb) do {                                                 \
    _Pragma("unroll") for (int n = 0; n < 2; ++n) {                            \
      const int br = wc64 + (nh)*32 + n * 16 + lm;                             \
      vb[n][0] = *(const half8*)&Bs[buf][br * 64 + pos0];                      \
      vb[n][1] = *(const half8*)&Bs[buf][br * 64 + pos1];                      \
    } } while (0)
#define MF_Q(mh, nh, vb) do {                                                  \
    _Pragma("unroll") for (int kk = 0; kk < 2; ++kk)                           \
    _Pragma("unroll") for (int m = 0; m < 4; ++m)                              \
    _Pragma("unroll") for (int n = 0; n < 2; ++n)                              \
      acc[(mh)*4+m][(nh)*2+n] = __builtin_amdgcn_mfma_f32_16x16x32_f16(        \
          va[m][kk], vb[n][kk], acc[(mh)*4+m][(nh)*2+n], 0, 0, 0);             \
  } while (0)

  ST_A(0, 0, 0); ST_A(0, 1, 0);
  ST_B(0, 0, 0); ST_B(0, 1, 0);
  ST_B(1, 0, 1); ST_B(1, 1, 1);
  VM4;
  BAR;

#pragma unroll 1
  for (int i = 0; i < 8; ++i) {
    const int st1 = (2 * i + 1 < 15) ? 2 * i + 1 : 15;
    const int st2 = (2 * i + 2 < 15) ? 2 * i + 2 : 15;
    const int st3 = (2 * i + 3 < 15) ? 2 * i + 3 : 15;
    // ---- P1
    RD_A(0, 0); RD_B(0, 0, vb0);
    ST_A(1, 0, st1);
    LGKM8;
    BAR; LGKM0;
    PRIO1; MF_Q(0, 0, vb0); PRIO0;
    BAR;
    // ---- P2
    RD_B(0, 1, vb1);
    ST_A(1, 1, st1);
    BAR; LGKM0;
    PRIO1; MF_Q(0, 1, vb1); PRIO0;
    BAR;
    // ---- P3
    RD_A(0, 1);
    ST_B(0, 0, st2);
    BAR; LGKM0;
    PRIO1; MF_Q(1, 0, vb0); PRIO0;
    BAR;
    // ---- P4
    ST_B(0, 1, st2);
    BAR; LGKM0;
    PRIO1; MF_Q(1, 1, vb1); PRIO0;
    VM4;
    BAR;
    // ---- P5
    RD_A(1, 0); RD_B(1, 0, vb0);
    ST_A(0, 0, st2);
    LGKM8;
    BAR; LGKM0;
    PRIO1; MF_Q(0, 0, vb0); PRIO0;
    BAR;
    // ---- P6
    RD_B(1, 1, vb1);
    ST_A(0, 1, st2);
    BAR; LGKM0;
    PRIO1; MF_Q(0, 1, vb1); PRIO0;
    BAR;
    // ---- P7
    RD_A(1, 1);
    ST_B(1, 0, st3);
    BAR; LGKM0;
    PRIO1; MF_Q(1, 0, vb0); PRIO0;
    BAR;
    // ---- P8
    ST_B(1, 1, st3);
    BAR; LGKM0;
    PRIO1; MF_Q(1, 1, vb1); PRIO0;
    VM4;
    BAR;
  }

  const float scale = 1.0f / 32.0f;
#pragma unroll
  for (int m = 0; m < 8; ++m)
#pragma unroll
    for (int r = 0; r < 4; ++r) {
      const int row = m0 + wr128 + m * 16 + lq * 4 + r;
      float s = 0.f;
#pragma unroll
      for (int n = 0; n < 4; ++n) {
        const int col = n0 + wc64 + n * 16 + lm;
        float v = __expf(acc[m][n][r] * scale - 8.0f);
        s += v;
        C[(size_t)row * 2048 + col] = (half_t)v;
      }
      s += __shfl_xor(s, 1); s += __shfl_xor(s, 2);
      s += __shfl_xor(s, 4); s += __shfl_xor(s, 8);
      if (lm == 0)
        lpart[((size_t)z * 2048 + row) * 32 + bx * 4 + (wave & 3)] = s;
    }
#undef ST_A
#undef ST_B
#undef RD_A
#undef RD_B
#undef MF_Q
}

// ---------- pv: out = (P @ V) / l, 128x256 tile, 4-phase, K=2048 ------------
// Grid 256 x 512 threads (1 clean round). id: x=id&7 (XCD), j=id>>3 (0..31).
__global__ __launch_bounds__(512, 2) void pv_gemm8(
    const half_t* __restrict__ sc, const half_t* __restrict__ vtg,
    float* __restrict__ out, const float* __restrict__ lpart) {
  __shared__ __align__(16) half_t As[2][128 * 64];
  __shared__ __align__(16) half_t Bs[2][256 * 64];
  __shared__ float linv[128];

  const int id = blockIdx.x;
  const int x  = id & 7, j = id >> 3;
  const int z  = x >> 1;
  const int m0 = ((x & 1) * 8 + (j >> 2)) * 128;   // P row-tile (of 2048)
  const int n0 = (j & 3) * 256;                    // d-tile (of 1024)
  const half_t* A  = sc  + (size_t)z * 2048 * 2048;  // P rows, ld 2048
  const half_t* Bm = vtg + (size_t)z * 2048;         // V^T rows (d), ld 8192
  float* C = out + (size_t)z * 2048 * 1024;

  const int t    = threadIdx.x;
  const int lane = t & 63;
  const int wave = t >> 6;
  const int wmv  = (wave >> 2) * 64;
  const int wnv  = (wave & 3) * 64;
  const int lm   = lane & 15;
  const int lq   = lane >> 4;
  const int pos0 = (lq ^ (lm & 7)) * 8;
  const int pos1 = ((4 + lq) ^ (lm & 7)) * 8;
  const int t8   = t * 8;

  if (t < 128) {
    const float4* lp = (const float4*)&lpart[((size_t)z * 2048 + m0 + t) * 32];
    float s = 0.f;
#pragma unroll
    for (int p = 0; p < 8; ++p) {
      float4 v = lp[p];
      s += v.x + v.y + v.z + v.w;
    }
    linv[t] = 1.0f / s;
  }

  const int trow = t >> 3;
  const int tchk = (t & 7) ^ (trow & 7);
  const half_t* gA2 = A  + (size_t)(m0 + trow) * 2048 + tchk * 8;
  const half_t* gB2 = Bm + (size_t)(n0 + trow) * 8192 + tchk * 8;

  f32x4 acc2[4][4] = {};
  half8 va[4][2], vb0[2][2], vb1[2][2];

#define ST_A2(buf, kt) do {                                                    \
    load16_to_lds(gA2 + (size_t)(kt) * 64, &As[buf][0] + t8);                  \
    load16_to_lds(gA2 + (size_t)64 * 2048 + (size_t)(kt) * 64,                 \
                  &As[buf][64*64] + t8);                                       \
  } while (0)
#define ST_B2(buf, h, kt) do {                                                 \
    load16_to_lds(gB2 + (size_t)((h)*128) * 8192 + (size_t)(kt) * 64,          \
                  &Bs[buf][(h)*128*64] + t8);                                  \
    load16_to_lds(gB2 + (size_t)((h)*128+64) * 8192 + (size_t)(kt) * 64,       \
                  &Bs[buf][((h)*128+64)*64] + t8);                             \
  } while (0)
#define RD_A2(buf, mh) do {                                                    \
    _Pragma("unroll") for (int m = 0; m < 2; ++m) {                            \
      const int ar = wmv + (mh)*32 + m * 16 + lm;                              \
      va[(mh)*2+m][0] = *(const half8*)&As[buf][ar * 64 + pos0];               \
      va[(mh)*2+m][1] = *(const half8*)&As[buf][ar * 64 + pos1];               \
    } } while (0)
#define RD_B2(buf, nh, vb) do {                                                \
    _Pragma("unroll") for (int n = 0; n < 2; ++n) {                            \
      const int br = wnv + (nh)*32 + n * 16 + lm;                              \
      vb[n][0] = *(const half8*)&Bs[buf][br * 64 + pos0];                      \
      vb[n][1] = *(const half8*)&Bs[buf][br * 64 + pos1];                      \
    } } while (0)
#define MF_V(mh, nh, vb) do {                                                  \
    _Pragma("unroll") for (int kk = 0; kk < 2; ++kk)                           \
    _Pragma("unroll") for (int m = 0; m < 2; ++m)                              \
    _Pragma("unroll") for (int n = 0; n < 2; ++n)                              \
      acc2[(mh)*2+m][(nh)*2+n] = __builtin_amdgcn_mfma_f32_16x16x32_f16(       \
          va[(mh)*2+m][kk], vb[n][kk], acc2[(mh)*2+m][(nh)*2+n], 0, 0, 0);     \
  } while (0)

  ST_B2(0, 0, 0); ST_B2(0, 1, 0); ST_A2(0, 0);   // b0 <- K-tile 0
  ST_B2(1, 0, 1); ST_B2(1, 1, 1); ST_A2(1, 1);   // b1 <- K-tile 1
  VM6;
  BAR;

#pragma unroll 1
  for (int i = 0; i < 16; ++i) {
    const int t2 = (2 * i + 2 < 31) ? 2 * i + 2 : 31;
    const int t3 = (2 * i + 3 < 31) ? 2 * i + 3 : 31;
    // ---- Pa: read ALL buf0 frags; MFMA first half
    RD_A2(0, 0); RD_A2(0, 1); RD_B2(0, 0, vb0); RD_B2(0, 1, vb1);
    LGKM8;
    BAR; LGKM0;
    PRIO1; MF_V(0, 0, vb0); MF_V(0, 1, vb1); PRIO0;
    BAR;
    // ---- Pb: stage buf0<-t2; MFMA second half; drain prev buf1 loads
    ST_B2(0, 0, t2); ST_B2(0, 1, t2); ST_A2(0, t2);
    PRIO1; MF_V(1, 0, vb0); MF_V(1, 1, vb1); PRIO0;
    VM6;
    BAR;
    // ---- Pc: read ALL buf1 frags; MFMA first half
    RD_A2(1, 0); RD_A2(1, 1); RD_B2(1, 0, vb0); RD_B2(1, 1, vb1);
    LGKM8;
    BAR; LGKM0;
    PRIO1; MF_V(0, 0, vb0); MF_V(0, 1, vb1); PRIO0;
    BAR;
    // ---- Pd: stage buf1<-t3; MFMA second half; drain Pb's buf0 loads
    ST_B2(1, 0, t3); ST_B2(1, 1, t3); ST_A2(1, t3);
    PRIO1; MF_V(1, 0, vb0); MF_V(1, 1, vb1); PRIO0;
    VM6;
    BAR;
  }

#pragma unroll
  for (int m = 0; m < 4; ++m)
#pragma unroll
    for (int r = 0; r < 4; ++r) {
      const int lrow = wmv + m * 16 + lq * 4 + r;
      const float inv = linv[lrow];
      const int row = m0 + lrow;
#pragma unroll
      for (int n = 0; n < 4; ++n) {
        const int col = n0 + wnv + n * 16 + lm;
        C[(size_t)row * 1024 + col] = acc2[m][n][r] * inv;
      }
    }
#undef ST_A2
#undef ST_B2
#undef RD_A2
#undef RD_B2
#undef MF_V
}

// --------------- prep: cast x + transpose weights (1 launch) -----------------
__global__ __launch_bounds__(256) void prep(
    const float* __restrict__ x, half_t* __restrict__ xh,
    const float* __restrict__ Wq, const float* __restrict__ Wk,
    const float* __restrict__ Wv, half_t* __restrict__ wt) {
  __shared__ half_t tile[32][33];
  const int b = blockIdx.x;
  const int t = threadIdx.x;
  if (b < 8192) {
    const int i = (b * 256 + t) * 4;
    const float4 v = *reinterpret_cast<const float4*>(x + i);
    half4v o;
    o.x = (half_t)v.x; o.y = (half_t)v.y; o.z = (half_t)v.z; o.w = (half_t)v.w;
    *reinterpret_cast<half4v*>(xh + i) = o;
  } else {
    int bb = b - 8192;
    const int w = bb >> 10; bb &= 1023;
    const float* in = (w == 0) ? Wq : (w == 1) ? Wk : Wv;
    half_t* o = wt + (size_t)w * 1024 * 1024;
    const int r0 = (bb >> 5) * 32, c0 = (bb & 31) * 32;
    const int tx = t & 31, ty = t >> 5;
#pragma unroll
    for (int i = 0; i < 32; i += 8)
      tile[ty + i][tx] = (half_t)in[(size_t)(r0 + ty + i) * 1024 + c0 + tx];
    __syncthreads();
#pragma unroll
    for (int i = 0; i < 32; i += 8)
      o[(size_t)(c0 + ty + i) * 1024 + r0 + tx] = tile[tx][ty + i];
  }
}

extern "C" void kernel_launch(void* const* d_in, const int* in_sizes, int n_in,
                              void* d_out, int out_size, void* d_ws, size_t ws_size,
                              hipStream_t stream) {
  constexpr int Bb = 4, S = 2048, D = 1024;
  constexpr size_t MS = (size_t)Bb * S;  // 8192 rows

  const float* x  = (const float*)d_in[0];
  const float* Wq = (const float*)d_in[1];
  const float* Wk = (const float*)d_in[2];
  const float* Wv = (const float*)d_in[3];
  float* out = (float*)d_out;

  // Workspace carve (~103 MB).
  char* p = (char*)d_ws;
  half_t* xh    = (half_t*)p; p += MS * D * 2;               // 16 MB
  half_t* wt    = (half_t*)p; p += (size_t)3 * D * D * 2;    // 6 MB  [Wq|Wk|Wv]^T
  half_t* qk    = (half_t*)p; p += MS * (size_t)(2 * D) * 2; // 32 MB [B*S, 2D]
  half_t* vtg   = (half_t*)p; p += (size_t)D * MS * 2;       // 16 MB [D, B*S]
  half_t* sc    = (half_t*)p; p += (size_t)Bb * S * S * 2;   // 32 MB P=exp(s-8)
  float*  lpart = (float*)p;  p += MS * 32 * 4;              // 1 MB partial sums

  prep<<<11264, 256, 0, stream>>>(x, xh, Wq, Wk, Wv, wt);
  qkvt_gemm8<<<256, 512, 0, stream>>>(xh, wt, qk, vtg);
  scores_gemm8<<<256, 512, 0, stream>>>(qk, sc, lpart);
  pv_gemm8<<<256, 512, 0, stream>>>(sc, vtg, out, lpart);
}

// Round 8
// 222.225 us; speedup vs baseline: 1.4802x; 1.0056x over previous
//
#include <hip/hip_runtime.h>
#include <hip/hip_bf16.h>

// SelfAttention: B=4, S=2048, D=1024, fp32 in/out.
// Round 16 = exact revert to R13 (best measured: 219.3us).
// R14 (cooperative fusion): +110us — grid.sync serialization + XCD-L2
// writeback makes fused slower than sum of parts. R15 (4-phase merge):
// +4us — reproduced learn_hip m196 (coarse phase-split hurts).
//  - qkvt_gemm8: QK 256x256 8-phase + VT 128x256 8-phase half-tile
//    (61.4us, 840 TF = demonstrated K=1024 template ceiling, m248).
//  - scores_gemm8: 256x256 8-phase, exp epilogue + lpart partials.
//  - pv_gemm8: 128x256 8-phase K=2048, /l epilogue.
//  - prep: cast x + 3 weight transposes (BW-bound floor ~13us).
// 4 launches: prep, qkvt8, scores8, pv8.

typedef _Float16 half_t;
typedef _Float16 half8 __attribute__((ext_vector_type(8)));
typedef _Float16 half4v __attribute__((ext_vector_type(4)));
typedef float f32x4 __attribute__((ext_vector_type(4)));

__device__ __forceinline__ void load16_to_lds(const half_t* g, half_t* l) {
  __builtin_amdgcn_global_load_lds(
      (const __attribute__((address_space(1))) void*)g,
      (__attribute__((address_space(3))) void*)l, 16, 0, 0);
}

#define LGKM0 asm volatile("s_waitcnt lgkmcnt(0)" ::: "memory")
#define LGKM8 asm volatile("s_waitcnt lgkmcnt(8)" ::: "memory")
#define VM0   asm volatile("s_waitcnt vmcnt(0)" ::: "memory")
#define VM4   asm volatile("s_waitcnt vmcnt(4)" ::: "memory")
#define VM6   asm volatile("s_waitcnt vmcnt(6)" ::: "memory")
#define BAR   __builtin_amdgcn_s_barrier()
#define PRIO1 __builtin_amdgcn_s_setprio(1)
#define PRIO0 __builtin_amdgcn_s_setprio(0)

// --------- qkvt: QK 256x256 tile + VT 128x256 half-tile per block ----------
// Grid 256 x 512 threads. x = b&7 (XCD), j = b>>3.
// QK: qk[8192,2048] = x @ [Wq|Wk]^T; m0=(x*4+(j&3))*256, n0=(j>>2)*256.
// VT: vtg[1024,8192] = Wv^T @ x^T;  m0v=(j>>2)*128, n0v=(x*4+(j&3))*256.
__global__ __launch_bounds__(512, 2) void qkvt_gemm8(
    const half_t* __restrict__ xh, const half_t* __restrict__ wt,
    half_t* __restrict__ qk, half_t* __restrict__ vtg) {
  __shared__ __align__(16) half_t As[2][256 * 64];
  __shared__ __align__(16) half_t Bs[2][256 * 64];

  const int b = blockIdx.x;
  const int x = b & 7, j = b >> 3;
  const int m0 = (x * 4 + (j & 3)) * 256;
  const int n0 = (j >> 2) * 256;

  const int t     = threadIdx.x;
  const int lane  = t & 63;
  const int wave  = t >> 6;
  const int wr128 = (wave >> 2) * 128;
  const int wc64  = (wave & 3) * 64;
  const int lm    = lane & 15;
  const int lq    = lane >> 4;
  const int pos0  = (lq ^ (lm & 7)) * 8;
  const int pos1  = ((4 + lq) ^ (lm & 7)) * 8;
  const int t8    = t * 8;

  const int trow = t >> 3;
  const int tchk = (t & 7) ^ (trow & 7);
  const half_t* gA0 = xh + (size_t)(m0 + trow) * 1024 + tchk * 8;
  const half_t* gB0 = wt + (size_t)(n0 + trow) * 1024 + tchk * 8;

  f32x4 acc[8][4] = {};
  half8 va[4][2], vb0[2][2], vb1[2][2];

#define ST_A(buf, h, kt) do {                                                  \
    load16_to_lds(gA0 + (size_t)((h)*128) * 1024 + (size_t)(kt) * 64,          \
                  &As[buf][(h)*128*64] + t8);                                  \
    load16_to_lds(gA0 + (size_t)((h)*128+64) * 1024 + (size_t)(kt) * 64,       \
                  &As[buf][((h)*128+64)*64] + t8);                             \
  } while (0)
#define ST_B(buf, h, kt) do {                                                  \
    load16_to_lds(gB0 + (size_t)((h)*128) * 1024 + (size_t)(kt) * 64,          \
                  &Bs[buf][(h)*128*64] + t8);                                  \
    load16_to_lds(gB0 + (size_t)((h)*128+64) * 1024 + (size_t)(kt) * 64,       \
                  &Bs[buf][((h)*128+64)*64] + t8);                             \
  } while (0)
#define RD_A(buf, mh) do {                                                     \
    _Pragma("unroll") for (int m = 0; m < 4; ++m) {                            \
      const int ar = wr128 + (mh)*64 + m * 16 + lm;                            \
      va[m][0] = *(const half8*)&As[buf][ar * 64 + pos0];                      \
      va[m][1] = *(const half8*)&As[buf][ar * 64 + pos1];                      \
    } } while (0)
#define RD_B(buf, nh, vb) do {                                                 \
    _Pragma("unroll") for (int n = 0; n < 2; ++n) {                            \
      const int br = wc64 + (nh)*32 + n * 16 + lm;                             \
      vb[n][0] = *(const half8*)&Bs[buf][br * 64 + pos0];                      \
      vb[n][1] = *(const half8*)&Bs[buf][br * 64 + pos1];                      \
    } } while (0)
#define MF_Q(mh, nh, vb) do {                                                  \
    _Pragma("unroll") for (int kk = 0; kk < 2; ++kk)                           \
    _Pragma("unroll") for (int m = 0; m < 4; ++m)                              \
    _Pragma("unroll") for (int n = 0; n < 2; ++n)                              \
      acc[(mh)*4+m][(nh)*2+n] = __builtin_amdgcn_mfma_f32_16x16x32_f16(        \
          va[m][kk], vb[n][kk], acc[(mh)*4+m][(nh)*2+n], 0, 0, 0);             \
  } while (0)

  ST_A(0, 0, 0); ST_A(0, 1, 0);
  ST_B(0, 0, 0); ST_B(0, 1, 0);
  ST_B(1, 0, 1); ST_B(1, 1, 1);
  VM4;
  BAR;

#pragma unroll 1
  for (int i = 0; i < 8; ++i) {
    const int st1 = (2 * i + 1 < 15) ? 2 * i + 1 : 15;
    const int st2 = (2 * i + 2 < 15) ? 2 * i + 2 : 15;
    const int st3 = (2 * i + 3 < 15) ? 2 * i + 3 : 15;
    // ---- P1
    RD_A(0, 0); RD_B(0, 0, vb0);
    ST_A(1, 0, st1);
    LGKM8;
    BAR; LGKM0;
    PRIO1; MF_Q(0, 0, vb0); PRIO0;
    BAR;
    // ---- P2
    RD_B(0, 1, vb1);
    ST_A(1, 1, st1);
    BAR; LGKM0;
    PRIO1; MF_Q(0, 1, vb1); PRIO0;
    BAR;
    // ---- P3
    RD_A(0, 1);
    ST_B(0, 0, st2);
    BAR; LGKM0;
    PRIO1; MF_Q(1, 0, vb0); PRIO0;
    BAR;
    // ---- P4
    ST_B(0, 1, st2);
    BAR; LGKM0;
    PRIO1; MF_Q(1, 1, vb1); PRIO0;
    VM4;
    BAR;
    // ---- P5
    RD_A(1, 0); RD_B(1, 0, vb0);
    ST_A(0, 0, st2);
    LGKM8;
    BAR; LGKM0;
    PRIO1; MF_Q(0, 0, vb0); PRIO0;
    BAR;
    // ---- P6
    RD_B(1, 1, vb1);
    ST_A(0, 1, st2);
    BAR; LGKM0;
    PRIO1; MF_Q(0, 1, vb1); PRIO0;
    BAR;
    // ---- P7
    RD_A(1, 1);
    ST_B(1, 0, st3);
    BAR; LGKM0;
    PRIO1; MF_Q(1, 0, vb0); PRIO0;
    BAR;
    // ---- P8
    ST_B(1, 1, st3);
    BAR; LGKM0;
    PRIO1; MF_Q(1, 1, vb1); PRIO0;
    VM4;
    BAR;
  }

  // 16x16 C/D: col=lane&15, row=(lane>>4)*4+reg  [m89/m91]
#pragma unroll
  for (int m = 0; m < 8; ++m)
#pragma unroll
    for (int n = 0; n < 4; ++n) {
      const int col = n0 + wc64 + n * 16 + lm;
#pragma unroll
      for (int r = 0; r < 4; ++r) {
        const int row = m0 + wr128 + m * 16 + lq * 4 + r;
        qk[(size_t)row * 2048 + col] = (half_t)acc[m][n][r];
      }
    }
#undef ST_A
#undef ST_B
#undef RD_A
#undef RD_B
#undef MF_Q

  // ======================= VT half-tile: 128x256, K=1024 ====================
  const int m0v = (j >> 2) * 128;
  const int n0v = (x * 4 + (j & 3)) * 256;
  const int wmv = (wave >> 2) * 64;   // 2 M-waves
  const int wnv = (wave & 3) * 64;    // 4 N-waves

  const half_t* gA2 = wt + (size_t)2 * 1024 * 1024 +
                      (size_t)(m0v + trow) * 1024 + tchk * 8;
  const half_t* gB2 = xh + (size_t)(n0v + trow) * 1024 + tchk * 8;

  f32x4 acc2[4][4] = {};

#define ST_A2(buf, kt) do {                                                    \
    load16_to_lds(gA2 + (size_t)(kt) * 64, &As[buf][0] + t8);                  \
    load16_to_lds(gA2 + (size_t)64 * 1024 + (size_t)(kt) * 64,                 \
                  &As[buf][64*64] + t8);                                       \
  } while (0)
#define ST_B2(buf, h, kt) do {                                                 \
    load16_to_lds(gB2 + (size_t)((h)*128) * 1024 + (size_t)(kt) * 64,          \
                  &Bs[buf][(h)*128*64] + t8);                                  \
    load16_to_lds(gB2 + (size_t)((h)*128+64) * 1024 + (size_t)(kt) * 64,       \
                  &Bs[buf][((h)*128+64)*64] + t8);                             \
  } while (0)
#define RD_A2(buf, mh) do {                                                    \
    _Pragma("unroll") for (int m = 0; m < 2; ++m) {                            \
      const int ar = wmv + (mh)*32 + m * 16 + lm;                              \
      va[(mh)*2+m][0] = *(const half8*)&As[buf][ar * 64 + pos0];               \
      va[(mh)*2+m][1] = *(const half8*)&As[buf][ar * 64 + pos1];               \
    } } while (0)
#define RD_B2(buf, nh, vb) do {                                                \
    _Pragma("unroll") for (int n = 0; n < 2; ++n) {                            \
      const int br = wnv + (nh)*32 + n * 16 + lm;                              \
      vb[n][0] = *(const half8*)&Bs[buf][br * 64 + pos0];                      \
      vb[n][1] = *(const half8*)&Bs[buf][br * 64 + pos1];                      \
    } } while (0)
#define MF_V(mh, nh, vb) do {                                                  \
    _Pragma("unroll") for (int kk = 0; kk < 2; ++kk)                           \
    _Pragma("unroll") for (int m = 0; m < 2; ++m)                              \
    _Pragma("unroll") for (int n = 0; n < 2; ++n)                              \
      acc2[(mh)*2+m][(nh)*2+n] = __builtin_amdgcn_mfma_f32_16x16x32_f16(       \
          va[(mh)*2+m][kk], vb[n][kk], acc2[(mh)*2+m][(nh)*2+n], 0, 0, 0);     \
  } while (0)

  // Drain QK's in-flight staged loads + epilogue stores before LDS reuse.
  VM0;
  ST_B2(0, 0, 0); ST_B2(0, 1, 0); ST_A2(0, 0);   // b0 <- K-tile 0
  ST_B2(1, 0, 1); ST_B2(1, 1, 1); ST_A2(1, 1);   // b1 <- K-tile 1
  VM6;
  BAR;

#pragma unroll 1
  for (int i = 0; i < 8; ++i) {
    const int t2 = (2 * i + 2 < 15) ? 2 * i + 2 : 15;
    const int t3 = (2 * i + 3 < 15) ? 2 * i + 3 : 15;
    // ---- P1
    RD_A2(0, 0); RD_B2(0, 0, vb0);
    BAR; LGKM0;
    PRIO1; MF_V(0, 0, vb0); PRIO0;
    BAR;
    // ---- P2
    RD_B2(0, 1, vb1);
    BAR; LGKM0;
    PRIO1; MF_V(0, 1, vb1); PRIO0;
    BAR;
    // ---- P3  (B(b0) reads done after P2-bar)
    RD_A2(0, 1);
    ST_B2(0, 0, t2);
    BAR; LGKM0;
    PRIO1; MF_V(1, 0, vb0); PRIO0;
    BAR;
    // ---- P4  (A(b0) reads done after P3-bar)
    ST_B2(0, 1, t2); ST_A2(0, t2);
    BAR; LGKM0;
    PRIO1; MF_V(1, 1, vb1); PRIO0;
    VM6;              // drains the 6 b1 loads (issued prev P7/P8 or prologue)
    BAR;
    // ---- P5
    RD_A2(1, 0); RD_B2(1, 0, vb0);
    BAR; LGKM0;
    PRIO1; MF_V(0, 0, vb0); PRIO0;
    BAR;
    // ---- P6
    RD_B2(1, 1, vb1);
    BAR; LGKM0;
    PRIO1; MF_V(0, 1, vb1); PRIO0;
    BAR;
    // ---- P7  (B(b1) reads done after P6-bar)
    RD_A2(1, 1);
    ST_B2(1, 0, t3);
    BAR; LGKM0;
    PRIO1; MF_V(1, 0, vb0); PRIO0;
    BAR;
    // ---- P8  (A(b1) reads done after P7-bar)
    ST_B2(1, 1, t3); ST_A2(1, t3);
    BAR; LGKM0;
    PRIO1; MF_V(1, 1, vb1); PRIO0;
    VM6;              // drains the 6 b0 loads (issued P3/P4)
    BAR;
  }

#pragma unroll
  for (int m = 0; m < 4; ++m)
#pragma unroll
    for (int n = 0; n < 4; ++n) {
      const int col = n0v + wnv + n * 16 + lm;
#pragma unroll
      for (int r = 0; r < 4; ++r) {
        const int row = m0v + wmv + m * 16 + lq * 4 + r;
        vtg[(size_t)row * 8192 + col] = (half_t)acc2[m][n][r];
      }
    }
#undef ST_A2
#undef ST_B2
#undef RD_A2
#undef RD_B2
#undef MF_V
}

// ------------- scores: P = exp(qk^T/32 - 8), 256x256 tile, 8-phase ----------
// 1D grid 256 blocks (exactly 1 round), 512 threads. XCD x: z=x>>1, by in
// {(x&1)*4..+3}, bx 0..7. Epilogue: exp(acc/32-8), 16-lane reduce,
// lpart slot = bx*4 + (wave&3)  (32 partials/row).
__global__ __launch_bounds__(512, 2) void scores_gemm8(
    const half_t* __restrict__ qk, half_t* __restrict__ sc,
    float* __restrict__ lpart) {
  __shared__ __align__(16) half_t As[2][256 * 64];
  __shared__ __align__(16) half_t Bs[2][256 * 64];

  const int id  = blockIdx.x;
  const int x   = id & 7, j = id >> 3;
  const int bx  = j & 7;
  const int z   = x >> 1;
  const int by  = (x & 1) * 4 + (j >> 3);
  const int m0  = by * 256;
  const int n0  = bx * 256;
  const half_t* A  = qk + (size_t)z * 2048 * 2048;  // q rows (ld 2048)
  const half_t* Bm = A + 1024;                      // k rows
  half_t* C = sc + (size_t)z * 2048 * 2048;

  const int t     = threadIdx.x;
  const int lane  = t & 63;
  const int wave  = t >> 6;
  const int wr128 = (wave >> 2) * 128;
  const int wc64  = (wave & 3) * 64;
  const int lm    = lane & 15;
  const int lq    = lane >> 4;
  const int pos0  = (lq ^ (lm & 7)) * 8;
  const int pos1  = ((4 + lq) ^ (lm & 7)) * 8;
  const int t8    = t * 8;

  const int trow = t >> 3;
  const int tchk = (t & 7) ^ (trow & 7);
  const half_t* gA0 = A  + (size_t)(m0 + trow) * 2048 + tchk * 8;
  const half_t* gB0 = Bm + (size_t)(n0 + trow) * 2048 + tchk * 8;

  f32x4 acc[8][4] = {};
  half8 va[4][2], vb0[2][2], vb1[2][2];

#define ST_A(buf, h, kt) do {                                                  \
    load16_to_lds(gA0 + (size_t)((h)*128) * 2048 + (size_t)(kt) * 64,          \
                  &As[buf][(h)*128*64] + t8);                                  \
    load16_to_lds(gA0 + (size_t)((h)*128+64) * 2048 + (size_t)(kt) * 64,       \
                  &As[buf][((h)*128+64)*64] + t8);                             \
  } while (0)
#define ST_B(buf, h, kt) do {                                                  \
    load16_to_lds(gB0 + (size_t)((h)*128) * 2048 + (size_t)(kt) * 64,          \
                  &Bs[buf][(h)*128*64] + t8);                                  \
    load16_to_lds(gB0 + (size_t)((h)*128+64) * 2048 + (size_t)(kt) * 64,       \
                  &Bs[buf][((h)*128+64)*64] + t8);                             \
  } while (0)
#define RD_A(buf, mh) do {                                                     \
    _Pragma("unroll") for (int m = 0; m < 4; ++m) {                            \
      const int ar = wr128 + (mh)*64 + m * 16 + lm;                            \
      va[m][0] = *(const half8*)&As[buf][ar * 64 + pos0];                      \
      va[m][1] = *(const half8*)&As[buf][ar * 64 + pos1];                      \
    } } while (0)
#define RD_B(buf, nh, vb) do {                                                 \
    _Pragma("unroll") for (int n = 0; n < 2; ++n) {                            \
      const int br = wc64 + (nh)*32 + n * 16 + lm;                             \
      vb[n][0] = *(const half8*)&Bs[buf][br * 64 + pos0];                      \
      vb[n][1] = *(const half8*)&Bs[buf][br * 64 + pos1];                      \
    } } while (0)
#define MF_Q(mh, nh, vb) do {                                                  \
    _Pragma("unroll") for (int kk = 0; kk < 2; ++kk)                           \
    _Pragma("unroll") for (int m = 0; m < 4; ++m)                              \
    _Pragma("unroll") for (int n = 0; n < 2; ++n)                              \
      acc[(mh)*4+m][(nh)*2+n] = __builtin_amdgcn_mfma_f32_16x16x32_f16(        \
          va[m][kk], vb[n][kk], acc[(mh)*4+m][(nh)*2+n], 0, 0, 0);             \
  } while (0)

  ST_A(0, 0, 0); ST_A(0, 1, 0);
  ST_B(0, 0, 0); ST_B(0, 1, 0);
  ST_B(1, 0, 1); ST_B(1, 1, 1);
  VM4;
  BAR;

#pragma unroll 1
  for (int i = 0; i < 8; ++i) {
    const int st1 = (2 * i + 1 < 15) ? 2 * i + 1 : 15;
    const int st2 = (2 * i + 2 < 15) ? 2 * i + 2 : 15;
    const int st3 = (2 * i + 3 < 15) ? 2 * i + 3 : 15;
    // ---- P1
    RD_A(0, 0); RD_B(0, 0, vb0);
    ST_A(1, 0, st1);
    LGKM8;
    BAR; LGKM0;
    PRIO1; MF_Q(0, 0, vb0); PRIO0;
    BAR;
    // ---- P2
    RD_B(0, 1, vb1);
    ST_A(1, 1, st1);
    BAR; LGKM0;
    PRIO1; MF_Q(0, 1, vb1); PRIO0;
    BAR;
    // ---- P3
    RD_A(0, 1);
    ST_B(0, 0, st2);
    BAR; LGKM0;
    PRIO1; MF_Q(1, 0, vb0); PRIO0;
    BAR;
    // ---- P4
    ST_B(0, 1, st2);
    BAR; LGKM0;
    PRIO1; MF_Q(1, 1, vb1); PRIO0;
    VM4;
    BAR;
    // ---- P5
    RD_A(1, 0); RD_B(1, 0, vb0);
    ST_A(0, 0, st2);
    LGKM8;
    BAR; LGKM0;
    PRIO1; MF_Q(0, 0, vb0); PRIO0;
    BAR;
    // ---- P6
    RD_B(1, 1, vb1);
    ST_A(0, 1, st2);
    BAR; LGKM0;
    PRIO1; MF_Q(0, 1, vb1); PRIO0;
    BAR;
    // ---- P7
    RD_A(1, 1);
    ST_B(1, 0, st3);
    BAR; LGKM0;
    PRIO1; MF_Q(1, 0, vb0); PRIO0;
    BAR;
    // ---- P8
    ST_B(1, 1, st3);
    BAR; LGKM0;
    PRIO1; MF_Q(1, 1, vb1); PRIO0;
    VM4;
    BAR;
  }

  const float scale = 1.0f / 32.0f;
#pragma unroll
  for (int m = 0; m < 8; ++m)
#pragma unroll
    for (int r = 0; r < 4; ++r) {
      const int row = m0 + wr128 + m * 16 + lq * 4 + r;
      float s = 0.f;
#pragma unroll
      for (int n = 0; n < 4; ++n) {
        const int col = n0 + wc64 + n * 16 + lm;
        float v = __expf(acc[m][n][r] * scale - 8.0f);
        s += v;
        C[(size_t)row * 2048 + col] = (half_t)v;
      }
      s += __shfl_xor(s, 1); s += __shfl_xor(s, 2);
      s += __shfl_xor(s, 4); s += __shfl_xor(s, 8);
      if (lm == 0)
        lpart[((size_t)z * 2048 + row) * 32 + bx * 4 + (wave & 3)] = s;
    }
#undef ST_A
#undef ST_B
#undef RD_A
#undef RD_B
#undef MF_Q
}

// ---------- pv: out = (P @ V) / l, 128x256 tile, 8-phase, K=2048 ------------
// Grid 256 x 512 threads (1 clean round). id: x=id&7 (XCD), j=id>>3 (0..31).
// z = x>>1; q-tile = (x&1)*8 + (j>>2) (16 per z); d-tile = j&3 (4 of 256).
// Consecutive j share the A-panel (P rows); B d-slab (1MB) L2-reused 8x.
__global__ __launch_bounds__(512, 2) void pv_gemm8(
    const half_t* __restrict__ sc, const half_t* __restrict__ vtg,
    float* __restrict__ out, const float* __restrict__ lpart) {
  __shared__ __align__(16) half_t As[2][128 * 64];
  __shared__ __align__(16) half_t Bs[2][256 * 64];
  __shared__ float linv[128];

  const int id = blockIdx.x;
  const int x  = id & 7, j = id >> 3;
  const int z  = x >> 1;
  const int m0 = ((x & 1) * 8 + (j >> 2)) * 128;   // P row-tile (of 2048)
  const int n0 = (j & 3) * 256;                    // d-tile (of 1024)
  const half_t* A  = sc  + (size_t)z * 2048 * 2048;  // P rows, ld 2048
  const half_t* Bm = vtg + (size_t)z * 2048;         // V^T rows (d), ld 8192
  float* C = out + (size_t)z * 2048 * 1024;

  const int t    = threadIdx.x;
  const int lane = t & 63;
  const int wave = t >> 6;
  const int wmv  = (wave >> 2) * 64;   // 2 M-wave groups (128 rows)
  const int wnv  = (wave & 3) * 64;    // 4 N-wave groups (256 cols)
  const int lm   = lane & 15;
  const int lq   = lane >> 4;
  const int pos0 = (lq ^ (lm & 7)) * 8;
  const int pos1 = ((4 + lq) ^ (lm & 7)) * 8;
  const int t8   = t * 8;

  // Reduce 32 per-row partials to 1/l (ready before epilogue: loop barriers)
  if (t < 128) {
    const float4* lp = (const float4*)&lpart[((size_t)z * 2048 + m0 + t) * 32];
    float s = 0.f;
#pragma unroll
    for (int p = 0; p < 8; ++p) {
      float4 v = lp[p];
      s += v.x + v.y + v.z + v.w;
    }
    linv[t] = 1.0f / s;
  }

  const int trow = t >> 3;
  const int tchk = (t & 7) ^ (trow & 7);
  const half_t* gA2 = A  + (size_t)(m0 + trow) * 2048 + tchk * 8;
  const half_t* gB2 = Bm + (size_t)(n0 + trow) * 8192 + tchk * 8;

  f32x4 acc2[4][4] = {};
  half8 va[4][2], vb0[2][2], vb1[2][2];

#define ST_A2(buf, kt) do {                                                    \
    load16_to_lds(gA2 + (size_t)(kt) * 64, &As[buf][0] + t8);                  \
    load16_to_lds(gA2 + (size_t)64 * 2048 + (size_t)(kt) * 64,                 \
                  &As[buf][64*64] + t8);                                       \
  } while (0)
#define ST_B2(buf, h, kt) do {                                                 \
    load16_to_lds(gB2 + (size_t)((h)*128) * 8192 + (size_t)(kt) * 64,          \
                  &Bs[buf][(h)*128*64] + t8);                                  \
    load16_to_lds(gB2 + (size_t)((h)*128+64) * 8192 + (size_t)(kt) * 64,       \
                  &Bs[buf][((h)*128+64)*64] + t8);                             \
  } while (0)
#define RD_A2(buf, mh) do {                                                    \
    _Pragma("unroll") for (int m = 0; m < 2; ++m) {                            \
      const int ar = wmv + (mh)*32 + m * 16 + lm;                              \
      va[(mh)*2+m][0] = *(const half8*)&As[buf][ar * 64 + pos0];               \
      va[(mh)*2+m][1] = *(const half8*)&As[buf][ar * 64 + pos1];               \
    } } while (0)
#define RD_B2(buf, nh, vb) do {                                                \
    _Pragma("unroll") for (int n = 0; n < 2; ++n) {                            \
      const int br = wnv + (nh)*32 + n * 16 + lm;                              \
      vb[n][0] = *(const half8*)&Bs[buf][br * 64 + pos0];                      \
      vb[n][1] = *(const half8*)&Bs[buf][br * 64 + pos1];                      \
    } } while (0)
#define MF_V(mh, nh, vb) do {                                                  \
    _Pragma("unroll") for (int kk = 0; kk < 2; ++kk)                           \
    _Pragma("unroll") for (int m = 0; m < 2; ++m)                              \
    _Pragma("unroll") for (int n = 0; n < 2; ++n)                              \
      acc2[(mh)*2+m][(nh)*2+n] = __builtin_amdgcn_mfma_f32_16x16x32_f16(       \
          va[(mh)*2+m][kk], vb[n][kk], acc2[(mh)*2+m][(nh)*2+n], 0, 0, 0);     \
  } while (0)

  ST_B2(0, 0, 0); ST_B2(0, 1, 0); ST_A2(0, 0);   // b0 <- K-tile 0
  ST_B2(1, 0, 1); ST_B2(1, 1, 1); ST_A2(1, 1);   // b1 <- K-tile 1
  VM6;
  BAR;

#pragma unroll 1
  for (int i = 0; i < 16; ++i) {
    const int t2 = (2 * i + 2 < 31) ? 2 * i + 2 : 31;
    const int t3 = (2 * i + 3 < 31) ? 2 * i + 3 : 31;
    // ---- P1
    RD_A2(0, 0); RD_B2(0, 0, vb0);
    BAR; LGKM0;
    PRIO1; MF_V(0, 0, vb0); PRIO0;
    BAR;
    // ---- P2
    RD_B2(0, 1, vb1);
    BAR; LGKM0;
    PRIO1; MF_V(0, 1, vb1); PRIO0;
    BAR;
    // ---- P3  (B(b0) reads done after P2-bar)
    RD_A2(0, 1);
    ST_B2(0, 0, t2);
    BAR; LGKM0;
    PRIO1; MF_V(1, 0, vb0); PRIO0;
    BAR;
    // ---- P4  (A(b0) reads done after P3-bar)
    ST_B2(0, 1, t2); ST_A2(0, t2);
    BAR; LGKM0;
    PRIO1; MF_V(1, 1, vb1); PRIO0;
    VM6;              // drains the 6 b1 loads (issued prev P7/P8 or prologue)
    BAR;
    // ---- P5
    RD_A2(1, 0); RD_B2(1, 0, vb0);
    BAR; LGKM0;
    PRIO1; MF_V(0, 0, vb0); PRIO0;
    BAR;
    // ---- P6
    RD_B2(1, 1, vb1);
    BAR; LGKM0;
    PRIO1; MF_V(0, 1, vb1); PRIO0;
    BAR;
    // ---- P7  (B(b1) reads done after P6-bar)
    RD_A2(1, 1);
    ST_B2(1, 0, t3);
    BAR; LGKM0;
    PRIO1; MF_V(1, 0, vb0); PRIO0;
    BAR;
    // ---- P8  (A(b1) reads done after P7-bar)
    ST_B2(1, 1, t3); ST_A2(1, t3);
    BAR; LGKM0;
    PRIO1; MF_V(1, 1, vb1); PRIO0;
    VM6;              // drains the 6 b0 loads (issued P3/P4)
    BAR;
  }

#pragma unroll
  for (int m = 0; m < 4; ++m)
#pragma unroll
    for (int r = 0; r < 4; ++r) {
      const int lrow = wmv + m * 16 + lq * 4 + r;
      const float inv = linv[lrow];
      const int row = m0 + lrow;
#pragma unroll
      for (int n = 0; n < 4; ++n) {
        const int col = n0 + wnv + n * 16 + lm;
        C[(size_t)row * 1024 + col] = acc2[m][n][r] * inv;
      }
    }
#undef ST_A2
#undef ST_B2
#undef RD_A2
#undef RD_B2
#undef MF_V
}

// --------------- prep: cast x + transpose weights (1 launch) -----------------
__global__ __launch_bounds__(256) void prep(
    const float* __restrict__ x, half_t* __restrict__ xh,
    const float* __restrict__ Wq, const float* __restrict__ Wk,
    const float* __restrict__ Wv, half_t* __restrict__ wt) {
  __shared__ half_t tile[32][33];
  const int b = blockIdx.x;
  const int t = threadIdx.x;
  if (b < 8192) {
    const int i = (b * 256 + t) * 4;
    const float4 v = *reinterpret_cast<const float4*>(x + i);
    half4v o;
    o.x = (half_t)v.x; o.y = (half_t)v.y; o.z = (half_t)v.z; o.w = (half_t)v.w;
    *reinterpret_cast<half4v*>(xh + i) = o;
  } else {
    int bb = b - 8192;
    const int w = bb >> 10; bb &= 1023;
    const float* in = (w == 0) ? Wq : (w == 1) ? Wk : Wv;
    half_t* o = wt + (size_t)w * 1024 * 1024;
    const int r0 = (bb >> 5) * 32, c0 = (bb & 31) * 32;
    const int tx = t & 31, ty = t >> 5;
#pragma unroll
    for (int i = 0; i < 32; i += 8)
      tile[ty + i][tx] = (half_t)in[(size_t)(r0 + ty + i) * 1024 + c0 + tx];
    __syncthreads();
#pragma unroll
    for (int i = 0; i < 32; i += 8)
      o[(size_t)(c0 + ty + i) * 1024 + r0 + tx] = tile[tx][ty + i];
  }
}

extern "C" void kernel_launch(void* const* d_in, const int* in_sizes, int n_in,
                              void* d_out, int out_size, void* d_ws, size_t ws_size,
                              hipStream_t stream) {
  constexpr int Bb = 4, S = 2048, D = 1024;
  constexpr size_t MS = (size_t)Bb * S;  // 8192 rows

  const float* x  = (const float*)d_in[0];
  const float* Wq = (const float*)d_in[1];
  const float* Wk = (const float*)d_in[2];
  const float* Wv = (const float*)d_in[3];
  float* out = (float*)d_out;

  // Workspace carve (~103 MB).
  char* p = (char*)d_ws;
  half_t* xh    = (half_t*)p; p += MS * D * 2;               // 16 MB
  half_t* wt    = (half_t*)p; p += (size_t)3 * D * D * 2;    // 6 MB  [Wq|Wk|Wv]^T
  half_t* qk    = (half_t*)p; p += MS * (size_t)(2 * D) * 2; // 32 MB [B*S, 2D]
  half_t* vtg   = (half_t*)p; p += (size_t)D * MS * 2;       // 16 MB [D, B*S]
  half_t* sc    = (half_t*)p; p += (size_t)Bb * S * S * 2;   // 32 MB P=exp(s-8)
  float*  lpart = (float*)p;  p += MS * 32 * 4;              // 1 MB partial sums

  prep<<<11264, 256, 0, stream>>>(x, xh, Wq, Wk, Wv, wt);
  qkvt_gemm8<<<256, 512, 0, stream>>>(xh, wt, qk, vtg);
  scores_gemm8<<<256, 512, 0, stream>>>(qk, sc, lpart);
  pv_gemm8<<<256, 512, 0, stream>>>(sc, vtg, out, lpart);
}